// Round 4
// baseline (518.162 us; speedup 1.0000x reference)
//
#include <hip/hip_runtime.h>
#include <hip/hip_bf16.h>

#define NN 8192
#define MM 128
#define EPSF 1e-4f
#define SHIFT 30.0f

typedef __bf16 bf16x8 __attribute__((ext_vector_type(8)));
typedef __bf16 bf16x4 __attribute__((ext_vector_type(4)));
typedef float floatx4 __attribute__((ext_vector_type(4)));

// fp32 -> bf16 conversion of out1 & out2 (blockIdx.y selects tensor)
__global__ void convert_kernel(const float* __restrict__ in0,
                               const float* __restrict__ in1,
                               __bf16* __restrict__ o0,
                               __bf16* __restrict__ o1) {
    const float* in = blockIdx.y ? in1 : in0;
    __bf16* out = blockIdx.y ? o1 : o0;
    int i = (blockIdx.x * blockDim.x + threadIdx.x) * 4;
    float4 v = *reinterpret_cast<const float4*>(in + i);
    bf16x4 o = { (__bf16)v.x, (__bf16)v.y, (__bf16)v.z, (__bf16)v.w };
    *reinterpret_cast<bf16x4*>(out + i) = o;
}

#define LOAD_A(dst, ptr)                                                   \
    do {                                                                   \
        dst[0] = *reinterpret_cast<const bf16x8*>((ptr) + 0);              \
        dst[1] = *reinterpret_cast<const bf16x8*>((ptr) + 32);             \
        dst[2] = *reinterpret_cast<const bf16x8*>((ptr) + 64);             \
        dst[3] = *reinterpret_cast<const bf16x8*>((ptr) + 96);             \
    } while (0)

// sums[0][i] = sum_j exp(S[i,j]-SHIFT) with S = out2 @ out1^T (dir 0)
// sums[1][j] = sum_i exp(S[i,j]-SHIFT)  (= row sums of out1 @ out2^T, dir 1)
// All 4 cg B-fragments batched per js for memory-level parallelism.
__global__ __launch_bounds__(256)
void rowsum_kernel(const __bf16* __restrict__ X2, const __bf16* __restrict__ X1,
                   float* __restrict__ sums) {
    const int dir = blockIdx.z;
    const __bf16* A = dir ? X1 : X2;
    const __bf16* B = dir ? X2 : X1;
    float* sum = sums + dir * NN;

    const int tid = threadIdx.x;
    const int w = tid >> 6, lane = tid & 63, q = lane >> 4, ln = lane & 15;
    const int i0 = blockIdx.y * 128 + w * 32;   // 32 rows per wave (2 row-groups)
    const int jbase = blockIdx.x * 1024;

    bf16x8 a[2][4];
    #pragma unroll
    for (int rg = 0; rg < 2; ++rg) {
        const __bf16* ar = A + (size_t)(i0 + rg * 16 + ln) * MM + q * 8;
        LOAD_A(a[rg], ar);
    }

    float p[2][4] = {{0.f, 0.f, 0.f, 0.f}, {0.f, 0.f, 0.f, 0.f}};

    for (int js = 0; js < 16; ++js) {
        const int j0 = jbase + js * 64;
        bf16x8 b[4][4];
        #pragma unroll
        for (int cg = 0; cg < 4; ++cg) {
            const __bf16* br = B + (size_t)(j0 + cg * 16 + ln) * MM + q * 8;
            LOAD_A(b[cg], br);
        }
        #pragma unroll
        for (int cg = 0; cg < 4; ++cg) {
            floatx4 acc0 = {0.f, 0.f, 0.f, 0.f};
            floatx4 acc1 = {0.f, 0.f, 0.f, 0.f};
            #pragma unroll
            for (int k = 0; k < 4; ++k) {
                acc0 = __builtin_amdgcn_mfma_f32_16x16x32_bf16(a[0][k], b[cg][k], acc0, 0, 0, 0);
                acc1 = __builtin_amdgcn_mfma_f32_16x16x32_bf16(a[1][k], b[cg][k], acc1, 0, 0, 0);
            }
            #pragma unroll
            for (int r = 0; r < 4; ++r) {
                p[0][r] += __expf(acc0[r] - SHIFT);
                p[1][r] += __expf(acc1[r] - SHIFT);
            }
        }
    }

    #pragma unroll
    for (int m = 1; m <= 8; m <<= 1) {
        #pragma unroll
        for (int rg = 0; rg < 2; ++rg)
            #pragma unroll
            for (int r = 0; r < 4; ++r)
                p[rg][r] += __shfl_xor(p[rg][r], m);
    }
    if (ln == 0) {
        #pragma unroll
        for (int rg = 0; rg < 2; ++rg)
            #pragma unroll
            for (int r = 0; r < 4; ++r)
                atomicAdd(&sum[i0 + rg * 16 + q * 4 + r], p[rg][r]);
    }
}

__global__ void recip_kernel(const float* __restrict__ s, float* __restrict__ r) {
    int i = blockIdx.x * 256 + threadIdx.x;
    r[i] = 1.0f / s[i];
}

// loss = sum_ij -label[i,j] * log( (e*rl_i+eps)*(e*rc_j+eps) ),  e = exp(s-SHIFT)
// TRANSPOSED MFMA: acc = mfma(b, a) computes the S^T tile, so each lane's 4
// acc regs are 4 CONSECUTIVE S-columns of ONE S-row (row = i0+rg*16+ln,
// cols = j0+cg*16+q*4+{0..3}). label and 1/colsum become float4 loads;
// 1/rowsum becomes one scalar per rg hoisted out of all loops.
__global__ __launch_bounds__(256)
void loss_kernel(const __bf16* __restrict__ A, const __bf16* __restrict__ B,
                 const float* __restrict__ lrowR, const float* __restrict__ lcolR,
                 const float* __restrict__ label, float* __restrict__ out) {
    const int tid = threadIdx.x;
    const int w = tid >> 6, lane = tid & 63, q = lane >> 4, ln = lane & 15;
    const int i0 = blockIdx.y * 128 + w * 32;   // 32 rows per wave
    const int jbase = blockIdx.x * 256;         // 256 cols per block

    bf16x8 a[2][4];
    float rl[2];
    const float* labp[2];
    #pragma unroll
    for (int rg = 0; rg < 2; ++rg) {
        const int row = i0 + rg * 16 + ln;
        LOAD_A(a[rg], A + (size_t)row * MM + q * 8);
        rl[rg] = lrowR[row];
        labp[rg] = label + (size_t)row * NN;
    }

    float lacc = 0.f;
    #pragma unroll
    for (int js = 0; js < 4; ++js) {
        const int j0 = jbase + js * 64;
        // batch all label/colsum vector loads for this 64-col step (MLP)
        floatx4 rc[4], lb[2][4];
        #pragma unroll
        for (int cg = 0; cg < 4; ++cg) {
            const int c4 = j0 + cg * 16 + q * 4;
            rc[cg] = *reinterpret_cast<const floatx4*>(&lcolR[c4]);
            lb[0][cg] = *reinterpret_cast<const floatx4*>(&labp[0][c4]);
            lb[1][cg] = *reinterpret_cast<const floatx4*>(&labp[1][c4]);
        }
        #pragma unroll
        for (int cg = 0; cg < 4; ++cg) {
            const __bf16* br = B + (size_t)(j0 + cg * 16 + ln) * MM + q * 8;
            bf16x8 b[4];
            LOAD_A(b, br);
            floatx4 acc0 = {0.f, 0.f, 0.f, 0.f};
            floatx4 acc1 = {0.f, 0.f, 0.f, 0.f};
            #pragma unroll
            for (int k = 0; k < 4; ++k) {
                acc0 = __builtin_amdgcn_mfma_f32_16x16x32_bf16(b[k], a[0][k], acc0, 0, 0, 0);
                acc1 = __builtin_amdgcn_mfma_f32_16x16x32_bf16(b[k], a[1][k], acc1, 0, 0, 0);
            }
            #pragma unroll
            for (int r = 0; r < 4; ++r) {
                float e0 = __expf(acc0[r] - SHIFT);
                float t0 = __logf(fmaf(e0, rl[0], EPSF) * fmaf(e0, rc[cg][r], EPSF));
                lacc = fmaf(lb[0][cg][r], t0, lacc);
                float e1 = __expf(acc1[r] - SHIFT);
                float t1 = __logf(fmaf(e1, rl[1], EPSF) * fmaf(e1, rc[cg][r], EPSF));
                lacc = fmaf(lb[1][cg][r], t1, lacc);
            }
        }
    }

    #pragma unroll
    for (int m = 1; m <= 32; m <<= 1) lacc += __shfl_xor(lacc, m);
    __shared__ float red[4];
    if (lane == 0) red[w] = lacc;
    __syncthreads();
    if (tid == 0) atomicAdd(out, -((red[0] + red[1]) + (red[2] + red[3])));
}

extern "C" void kernel_launch(void* const* d_in, const int* in_sizes, int n_in,
                              void* d_out, int out_size, void* d_ws, size_t ws_size,
                              hipStream_t stream) {
    const float* out1 = (const float*)d_in[0];
    const float* out2 = (const float*)d_in[1];
    const float* label = (const float*)d_in[2];

    char* ws = (char*)d_ws;
    __bf16* out1b = (__bf16*)ws;                          // 2 MB
    __bf16* out2b = (__bf16*)(ws + (size_t)(2 << 20));    // 2 MB
    float* sums   = (float*)(ws + (size_t)(4 << 20));     // 2*NN floats (64 KB)
    float* recips = sums + 2 * NN;                        // 2*NN floats (64 KB)

    hipMemsetAsync(sums, 0, 2 * NN * sizeof(float), stream);
    hipMemsetAsync(d_out, 0, sizeof(float), stream);

    convert_kernel<<<dim3(1024, 2), 256, 0, stream>>>(out1, out2, out1b, out2b);

    // both directions in one dispatch: z=0 row sums, z=1 col sums
    rowsum_kernel<<<dim3(8, 64, 2), 256, 0, stream>>>(out2b, out1b, sums);
    recip_kernel<<<dim3(64), 256, 0, stream>>>(sums, recips);

    loss_kernel<<<dim3(32, 64), 256, 0, stream>>>(out2b, out1b,
                                                  recips,          // 1/rowsum
                                                  recips + NN,     // 1/colsum
                                                  label, (float*)d_out);
}

// Round 5
// 459.073 us; speedup vs baseline: 1.1287x; 1.1287x over previous
//
#include <hip/hip_runtime.h>
#include <hip/hip_bf16.h>

#define NN 8192
#define MM 128
#define EPSF 1e-4f
#define SHIFT 30.0f

typedef __bf16 bf16x8 __attribute__((ext_vector_type(8)));
typedef __bf16 bf16x4 __attribute__((ext_vector_type(4)));
typedef float floatx4 __attribute__((ext_vector_type(4)));

// fp32 -> bf16 conversion of out1 & out2 (blockIdx.y selects tensor)
__global__ void convert_kernel(const float* __restrict__ in0,
                               const float* __restrict__ in1,
                               __bf16* __restrict__ o0,
                               __bf16* __restrict__ o1) {
    const float* in = blockIdx.y ? in1 : in0;
    __bf16* out = blockIdx.y ? o1 : o0;
    int i = (blockIdx.x * blockDim.x + threadIdx.x) * 4;
    float4 v = *reinterpret_cast<const float4*>(in + i);
    bf16x4 o = { (__bf16)v.x, (__bf16)v.y, (__bf16)v.z, (__bf16)v.w };
    *reinterpret_cast<bf16x4*>(out + i) = o;
}

#define LOAD_A(dst, ptr)                                                   \
    do {                                                                   \
        dst[0] = *reinterpret_cast<const bf16x8*>((ptr) + 0);              \
        dst[1] = *reinterpret_cast<const bf16x8*>((ptr) + 32);             \
        dst[2] = *reinterpret_cast<const bf16x8*>((ptr) + 64);             \
        dst[3] = *reinterpret_cast<const bf16x8*>((ptr) + 96);             \
    } while (0)

// ONE pass over S = A @ B^T (A=out2b, B=out1b), producing BOTH
// sums[0][i] = sum_j exp(S[i,j]-SHIFT) and sums[1][j] = sum_i exp(S[i,j]-SHIFT).
// Non-transposed MFMA layout: acc[r] = S[i0+rg*16+q*4+r][j0+cg*16+ln].
// Col partial (col=ln): in-lane adds over r,rg + shfl over q -> 1 atomic/cg.
// Row partial: per-lane accumulation, single cross-ln reduce at kernel end.
__global__ __launch_bounds__(256)
void sums_kernel(const __bf16* __restrict__ A, const __bf16* __restrict__ B,
                 float* __restrict__ sums) {
    const int tid = threadIdx.x;
    const int w = tid >> 6, lane = tid & 63, q = lane >> 4, ln = lane & 15;
    const int i0 = blockIdx.y * 128 + w * 32;   // 32 rows per wave (2 row-groups)
    const int jbase = blockIdx.x * 512;         // 512 cols per block

    const floatx4 accInit = {-SHIFT, -SHIFT, -SHIFT, -SHIFT};

    bf16x8 a[2][4];
    #pragma unroll
    for (int rg = 0; rg < 2; ++rg)
        LOAD_A(a[rg], A + (size_t)(i0 + rg * 16 + ln) * MM + q * 8);

    float p[2][4] = {{0.f, 0.f, 0.f, 0.f}, {0.f, 0.f, 0.f, 0.f}};

    for (int js = 0; js < 8; ++js) {
        const int j0 = jbase + js * 64;
        bf16x8 b[4][4];
        #pragma unroll
        for (int cg = 0; cg < 4; ++cg)
            LOAD_A(b[cg], B + (size_t)(j0 + cg * 16 + ln) * MM + q * 8);
        #pragma unroll
        for (int cg = 0; cg < 4; ++cg) {
            floatx4 acc0 = accInit, acc1 = accInit;
            #pragma unroll
            for (int k = 0; k < 4; ++k) {
                acc0 = __builtin_amdgcn_mfma_f32_16x16x32_bf16(a[0][k], b[cg][k], acc0, 0, 0, 0);
                acc1 = __builtin_amdgcn_mfma_f32_16x16x32_bf16(a[1][k], b[cg][k], acc1, 0, 0, 0);
            }
            float e0[4], e1[4];
            #pragma unroll
            for (int r = 0; r < 4; ++r) {
                e0[r] = __expf(acc0[r]);
                e1[r] = __expf(acc1[r]);
                p[0][r] += e0[r];
                p[1][r] += e1[r];
            }
            // column partial for col = j0+cg*16+ln: sum over r, rg, then q
            float c = ((e0[0] + e0[1]) + (e0[2] + e0[3])) +
                      ((e1[0] + e1[1]) + (e1[2] + e1[3]));
            c += __shfl_xor(c, 16);
            c += __shfl_xor(c, 32);
            if (q == 0) atomicAdd(&sums[NN + j0 + cg * 16 + ln], c);
        }
    }

    // row sums: reduce across the 16 ln-lanes (cols) of each quad
    #pragma unroll
    for (int m = 1; m <= 8; m <<= 1)
        #pragma unroll
        for (int rg = 0; rg < 2; ++rg)
            #pragma unroll
            for (int r = 0; r < 4; ++r)
                p[rg][r] += __shfl_xor(p[rg][r], m);
    if (ln == 0)
        #pragma unroll
        for (int rg = 0; rg < 2; ++rg)
            #pragma unroll
            for (int r = 0; r < 4; ++r)
                atomicAdd(&sums[i0 + rg * 16 + q * 4 + r], p[rg][r]);
}

__global__ void recip_kernel(const float* __restrict__ s, float* __restrict__ r) {
    int i = blockIdx.x * 256 + threadIdx.x;
    r[i] = 1.0f / s[i];
}

// loss = sum_ij -label[i,j] * log( (e*rl_i+eps)*(e*rc_j+eps) ),  e = exp(s-SHIFT)
// TRANSPOSED MFMA: acc = mfma(b, a) gives lane = one S-row, 4 consecutive
// S-cols per reg -> label & 1/colsum are float4 loads; 1/rowsum is scalar/rg.
__global__ __launch_bounds__(256)
void loss_kernel(const __bf16* __restrict__ A, const __bf16* __restrict__ B,
                 const float* __restrict__ lrowR, const float* __restrict__ lcolR,
                 const float* __restrict__ label, float* __restrict__ out) {
    const int tid = threadIdx.x;
    const int w = tid >> 6, lane = tid & 63, q = lane >> 4, ln = lane & 15;
    const int i0 = blockIdx.y * 128 + w * 32;   // 32 rows per wave
    const int jbase = blockIdx.x * 256;         // 256 cols per block

    const floatx4 accInit = {-SHIFT, -SHIFT, -SHIFT, -SHIFT};

    bf16x8 a[2][4];
    float rl[2];
    const float* labp[2];
    #pragma unroll
    for (int rg = 0; rg < 2; ++rg) {
        const int row = i0 + rg * 16 + ln;
        LOAD_A(a[rg], A + (size_t)row * MM + q * 8);
        rl[rg] = lrowR[row];
        labp[rg] = label + (size_t)row * NN;
    }

    float lacc = 0.f;
    #pragma unroll
    for (int js = 0; js < 4; ++js) {
        const int j0 = jbase + js * 64;
        floatx4 rc[4], lb[2][4];
        #pragma unroll
        for (int cg = 0; cg < 4; ++cg) {
            const int c4 = j0 + cg * 16 + q * 4;
            rc[cg] = *reinterpret_cast<const floatx4*>(&lcolR[c4]);
            lb[0][cg] = *reinterpret_cast<const floatx4*>(&labp[0][c4]);
            lb[1][cg] = *reinterpret_cast<const floatx4*>(&labp[1][c4]);
        }
        #pragma unroll
        for (int cg = 0; cg < 4; ++cg) {
            const __bf16* br = B + (size_t)(j0 + cg * 16 + ln) * MM + q * 8;
            bf16x8 b[4];
            LOAD_A(b, br);
            floatx4 acc0 = accInit, acc1 = accInit;
            #pragma unroll
            for (int k = 0; k < 4; ++k) {
                acc0 = __builtin_amdgcn_mfma_f32_16x16x32_bf16(b[k], a[0][k], acc0, 0, 0, 0);
                acc1 = __builtin_amdgcn_mfma_f32_16x16x32_bf16(b[k], a[1][k], acc1, 0, 0, 0);
            }
            #pragma unroll
            for (int r = 0; r < 4; ++r) {
                float e0 = __expf(acc0[r]);
                float t0 = __logf(fmaf(e0, rl[0], EPSF) * fmaf(e0, rc[cg][r], EPSF));
                lacc = fmaf(lb[0][cg][r], t0, lacc);
                float e1 = __expf(acc1[r]);
                float t1 = __logf(fmaf(e1, rl[1], EPSF) * fmaf(e1, rc[cg][r], EPSF));
                lacc = fmaf(lb[1][cg][r], t1, lacc);
            }
        }
    }

    #pragma unroll
    for (int m = 1; m <= 32; m <<= 1) lacc += __shfl_xor(lacc, m);
    __shared__ float red[4];
    if (lane == 0) red[w] = lacc;
    __syncthreads();
    if (tid == 0) atomicAdd(out, -((red[0] + red[1]) + (red[2] + red[3])));
}

extern "C" void kernel_launch(void* const* d_in, const int* in_sizes, int n_in,
                              void* d_out, int out_size, void* d_ws, size_t ws_size,
                              hipStream_t stream) {
    const float* out1 = (const float*)d_in[0];
    const float* out2 = (const float*)d_in[1];
    const float* label = (const float*)d_in[2];

    char* ws = (char*)d_ws;
    __bf16* out1b = (__bf16*)ws;                          // 2 MB
    __bf16* out2b = (__bf16*)(ws + (size_t)(2 << 20));    // 2 MB
    float* sums   = (float*)(ws + (size_t)(4 << 20));     // 2*NN floats (64 KB)
    float* recips = sums + 2 * NN;                        // 2*NN floats (64 KB)

    hipMemsetAsync(sums, 0, 2 * NN * sizeof(float), stream);
    hipMemsetAsync(d_out, 0, sizeof(float), stream);

    convert_kernel<<<dim3(1024, 2), 256, 0, stream>>>(out1, out2, out1b, out2b);

    // single S pass -> both row sums (sums[0:NN]) and col sums (sums[NN:2NN])
    sums_kernel<<<dim3(16, 64), 256, 0, stream>>>(out2b, out1b, sums);
    recip_kernel<<<dim3(64), 256, 0, stream>>>(sums, recips);

    loss_kernel<<<dim3(32, 64), 256, 0, stream>>>(out2b, out1b,
                                                  recips,          // 1/rowsum
                                                  recips + NN,     // 1/colsum
                                                  label, (float*)d_out);
}